// Round 4
// baseline (40364.905 us; speedup 1.0000x reference)
//
#include <hip/hip_runtime.h>
#include <math.h>
#include <cstddef>

#define G3 3072

__device__ __forceinline__ float sigmoidf_(float x){ return 1.0f/(1.0f+expf(-x)); }

__device__ __forceinline__ float gru_out_(float gi_r,float gh_r,float bir,float bhr,
                                          float gi_z,float gh_z,float biz,float bhz,
                                          float gi_n,float gh_n,float bin,float bhn,
                                          float dold)
{
    const float r = sigmoidf_(gi_r + gh_r + bir + bhr);
    const float z = sigmoidf_(gi_z + gh_z + biz + bhz);
    const float n = tanhf(gi_n + bin + r*(gh_n + bhn));
    return (1.f - z)*n + z*dold;
}

// ---------------------------------------------------------------------------
__global__ __launch_bounds__(256)
void zero_k(float* p, int n){
    int i = blockIdx.x*blockDim.x + threadIdx.x;
    for (int j = i; j < n; j += gridDim.x*blockDim.x) p[j] = 0.f;
}

// ---------------------------------------------------------------------------
// C[M x N] = A[M x K] @ B[K x N] (+bias). grid (N/64, M/16), block 256.
// Used for per-level Wqs fold and the per-level HC = ctx @ Wpc precompute.
__global__ __launch_bounds__(256)
void gemm_k(const float* __restrict__ A, long lda,
            const float* __restrict__ Bm, long ldb,
            const float* __restrict__ bias,
            float* __restrict__ C, long ldc, int K)
{
    __shared__ float xs[16][64];
    const int tid = threadIdx.x;
    const int nl = tid & 31, bl = tid >> 5;
    const int n  = blockIdx.x*64 + nl*2;
    const int m0 = blockIdx.y*16;
    float a0x=0.f,a0y=0.f,a1x=0.f,a1y=0.f;
    for (int kc = 0; kc < K; kc += 64) {
        __syncthreads();
        { int r = tid >> 4, c = (tid & 15)*4;
          *(float4*)&xs[r][c] = *(const float4*)&A[(size_t)(m0+r)*lda + kc + c]; }
        __syncthreads();
        #pragma unroll 8
        for (int kk = 0; kk < 64; ++kk) {
            const float2 w = *(const float2*)&Bm[(size_t)(kc+kk)*ldb + n];
            const float xa = xs[bl][kk], xb = xs[bl+8][kk];
            a0x += xa*w.x; a0y += xa*w.y;
            a1x += xb*w.x; a1y += xb*w.y;
        }
    }
    float bx=0.f, by=0.f;
    if (bias){ bx = bias[n]; by = bias[n+1]; }
    float* c0 = &C[(size_t)(m0+bl)*ldc + n];
    float* c1 = &C[(size_t)(m0+bl+8)*ldc + n];
    c0[0]=a0x+bx; c0[1]=a0y+by; c1[0]=a1x+bx; c1[1]=a1y+by;
}

// ---------------------------------------------------------------------------
// bps = bp + bqm @ Wp_s   (Wp_s = first 128 rows of Wp_l). 1 block x 512.
__global__ __launch_bounds__(512)
void bps_k(const float* __restrict__ bqm, const float* __restrict__ Wps,
           const float* __restrict__ bp, float* __restrict__ bps)
{
    const int n = threadIdx.x;
    float a = 0.f;
    #pragma unroll 8
    for (int k = 0; k < 128; ++k) a += bqm[k]*Wps[(size_t)k*512 + n];
    bps[n] = a + bp[n];
}

// ---------------------------------------------------------------------------
// Step stage A (t>0 only): one dispatch computing BOTH
//   blocks [0,384):   qp[cz][128][512] partials of det@Wq[0:1024]+obs@Wq[1024:1536]
//                     decode: x=bid&3 (4 n-tiles of 128), y=(bid>>2)&15, cz=bid>>6 (6)
//   blocks [384,1152): ghP[zc][128][3072] = det @ Whh K-chunk zc*128
//                     decode: g=bid-384; x=g%24, y=(g/24)&3, zc=g/96 (8)
__global__ __launch_bounds__(256)
void stepA_k(const float* __restrict__ det, long ld_det,   // det_{t-1}
             const float* __restrict__ obs, long ld_obs,   // obs_{t-1}
             const float* __restrict__ Wq,                  // 1536 x 512
             float* __restrict__ qp,                        // 6 x 128 x 512
             const float* __restrict__ Whh,                 // 1024 x 3072
             float* __restrict__ ghP)                       // 8 x 128 x 3072
{
    __shared__ float xs[32*132];
    const int tid = threadIdx.x;
    const int bid = blockIdx.x;
    if (bid < 384) {
        // ---- qp partial GEMM, K=256 per chunk, 4 cols/thread (float4 W) ----
        const int x = bid & 3, y = (bid>>2)&15, cz = bid>>6;
        const int nl = tid & 31, mg = tid >> 5;
        const int n  = x*128 + nl*4;
        const int m0 = y*8;
        const float* As; long lda; int kr0;
        if (cz < 4) { As = det + cz*256;     lda = ld_det; kr0 = cz*256; }
        else        { As = obs + (cz-4)*256; lda = ld_obs; kr0 = 1024 + (cz-4)*256; }
        {   // stage 8 rows x 256 cols
            const int r = tid >> 5, c = (tid & 31)*8;
            const float* src = &As[(size_t)(m0+r)*lda + c];
            *(float4*)&xs[r*256 + c]     = *(const float4*)&src[0];
            *(float4*)&xs[r*256 + c + 4] = *(const float4*)&src[4];
        }
        __syncthreads();
        const float* w = &Wq[(size_t)kr0*512 + n];
        float4 acc = make_float4(0.f,0.f,0.f,0.f);
        #pragma unroll 8
        for (int kk = 0; kk < 256; ++kk) {
            const float4 wv = *(const float4*)&w[(size_t)kk*512];
            const float xv = xs[mg*256 + kk];
            acc.x += xv*wv.x; acc.y += xv*wv.y;
            acc.z += xv*wv.z; acc.w += xv*wv.w;
        }
        *(float4*)&qp[(size_t)cz*65536 + (size_t)(m0+mg)*512 + n] = acc;
    } else {
        // ---- ghP partial GEMM: det @ Whh, 32 rows x 128 cols, K=128 ----
        const int g = bid - 384;
        const int x = g % 24, y = (g/24)&3, zc = g/96;
        const int nl = tid & 31, mg = tid >> 5;
        const int n  = x*128 + nl*4;
        const int m0 = y*32;
        const int kb = zc*128;
        {   // stage A-tile 32 rows x 128 cols
            const int r = tid >> 3, c0 = (tid & 7)*16;
            #pragma unroll
            for (int i = 0; i < 4; ++i) {
                const int c = c0 + i*4;
                *(float4*)&xs[r*132 + c] =
                    *(const float4*)&det[(size_t)(m0+r)*ld_det + kb + c];
            }
        }
        __syncthreads();
        const float* W = Whh + (size_t)kb*G3 + n;
        float* outp = ghP + (size_t)zc*393216;
        float4 acc[4];
        #pragma unroll
        for (int j = 0; j < 4; ++j) acc[j] = make_float4(0.f,0.f,0.f,0.f);
        const int rb = mg*4;
        #pragma unroll 2
        for (int kc4 = 0; kc4 < 128; kc4 += 4) {
            float4 xv[4];
            #pragma unroll
            for (int j = 0; j < 4; ++j)
                xv[j] = *(const float4*)&xs[(rb+j)*132 + kc4];
            #pragma unroll
            for (int kk = 0; kk < 4; ++kk) {
                const float4 wv = *(const float4*)&W[(size_t)(kc4+kk)*G3];
                #pragma unroll
                for (int j = 0; j < 4; ++j) {
                    const float xj = (kk==0) ? xv[j].x : (kk==1) ? xv[j].y
                                   : (kk==2) ? xv[j].z : xv[j].w;
                    acc[j].x += xj*wv.x; acc[j].y += xj*wv.y;
                    acc[j].z += xj*wv.z; acc[j].w += xj*wv.w;
                }
            }
        }
        #pragma unroll
        for (int j = 0; j < 4; ++j)
            *(float4*)&outp[(size_t)(m0+rb+j)*G3 + n] = acc[j];
    }
}

// ---------------------------------------------------------------------------
// hp[kz][128][512] partial of qh @ Wqs, qh = relu(sum qp + bq) built in-stage.
// grid (4, 16, 4), block 256; 4 cols/thread (float4 W).
__global__ __launch_bounds__(256)
void h_part_k(const float* __restrict__ qp, const float* __restrict__ bq,
              const float* __restrict__ Wqs, float* __restrict__ hp)
{
    __shared__ float xs[8*128];
    const int tid = threadIdx.x;
    const int nl = tid & 31, mg = tid >> 5;
    const int n  = blockIdx.x*128 + nl*4;
    const int m0 = blockIdx.y*8;
    const int kz = blockIdx.z;
    {   // stage: qh[m0..m0+7][kz*128..+127] = relu(sum qp + bq)
        const int r = tid >> 5, c = (tid & 31)*4;
        const int kg = kz*128 + c;
        float4 s = *(const float4*)&bq[kg];
        #pragma unroll
        for (int cc = 0; cc < 6; ++cc) {
            const float4 p = *(const float4*)&qp[(size_t)cc*65536 + (size_t)(m0+r)*512 + kg];
            s.x += p.x; s.y += p.y; s.z += p.z; s.w += p.w;
        }
        s.x = fmaxf(s.x,0.f); s.y = fmaxf(s.y,0.f);
        s.z = fmaxf(s.z,0.f); s.w = fmaxf(s.w,0.f);
        *(float4*)&xs[r*128 + c] = s;
    }
    __syncthreads();
    const float* w = &Wqs[(size_t)(kz*128)*512 + n];
    float4 acc = make_float4(0.f,0.f,0.f,0.f);
    #pragma unroll 8
    for (int kk = 0; kk < 128; ++kk) {
        const float4 wv = *(const float4*)&w[(size_t)kk*512];
        const float xv = xs[mg*128 + kk];
        acc.x += xv*wv.x; acc.y += xv*wv.y;
        acc.z += xv*wv.z; acc.w += xv*wv.w;
    }
    *(float4*)&hp[(size_t)kz*65536 + (size_t)(m0+mg)*512 + n] = acc;
}

// ---------------------------------------------------------------------------
// Step stage C: gi partial GEMM + fused GRU epilogue via last-arriver reduction.
// grid (24, 4, 4): x = col-tile (128 of 3072), y = row-tile (32 of 128),
// zc = K-chunk (4 x 128). Epi tile (dx = x%8, y) has exactly 12 contributor
// blocks (x in {dx, dx+8, dx+16} x zc 0..3); the 12th arriver reduces
// giP/ghP, applies the GRU nonlinearity, and writes det_out.
__global__ __launch_bounds__(256)
void stepC_k(const float* __restrict__ hp,        // 4x128x512, or null (t==0)
             const float* __restrict__ hc, long ld_hc,  // pre-offset; or null
             const float* __restrict__ hbias,     // bps (t>0) or bp (t==0)
             const float* __restrict__ det_in, long ld_det,   // det_{t-1} (unused t==0)
             const float* __restrict__ Wih,
             float* __restrict__ giP,             // 4 x 128 x 3072
             const float* __restrict__ ghP,       // 8 x 128 x 3072 (from stepA)
             const float* __restrict__ bih, const float* __restrict__ bhh,
             float* __restrict__ det_out, long ld_out,
             int have_gh, int* __restrict__ cnt)
{
    __shared__ float xs[32*132];
    __shared__ int last;
    const int tid = threadIdx.x;
    const int x = blockIdx.x, y = blockIdx.y, zc = blockIdx.z;
    const int nl = tid & 31, mg = tid >> 5;
    const int n  = x*128 + nl*4;
    const int m0 = y*32;
    {   // stage h-tile 32 rows x 128 cols: relu(sum hp + hc + bias)
        const int r = tid >> 3, c0 = (tid & 7)*16;
        const int kb = zc*128;
        #pragma unroll
        for (int i = 0; i < 4; ++i) {
            const int c = c0 + i*4, kg = kb + c;
            float4 s = *(const float4*)&hbias[kg];
            if (hc) {
                const float4 p = *(const float4*)&hc[(size_t)(m0+r)*ld_hc + kg];
                s.x+=p.x; s.y+=p.y; s.z+=p.z; s.w+=p.w;
            }
            if (hp) {
                #pragma unroll
                for (int cc = 0; cc < 4; ++cc) {
                    const float4 p = *(const float4*)&hp[(size_t)cc*65536 + (size_t)(m0+r)*512 + kg];
                    s.x+=p.x; s.y+=p.y; s.z+=p.z; s.w+=p.w;
                }
            }
            s.x=fmaxf(s.x,0.f); s.y=fmaxf(s.y,0.f);
            s.z=fmaxf(s.z,0.f); s.w=fmaxf(s.w,0.f);
            *(float4*)&xs[r*132 + c] = s;
        }
    }
    __syncthreads();
    {   // gi partial: 4 rows x 4 cols per thread, K=128
        const float* W = Wih + (size_t)(zc*128)*G3 + n;
        float* outp = giP + (size_t)zc*393216;
        float4 acc[4];
        #pragma unroll
        for (int j = 0; j < 4; ++j) acc[j] = make_float4(0.f,0.f,0.f,0.f);
        const int rb = mg*4;
        #pragma unroll 2
        for (int kc4 = 0; kc4 < 128; kc4 += 4) {
            float4 xv[4];
            #pragma unroll
            for (int j = 0; j < 4; ++j)
                xv[j] = *(const float4*)&xs[(rb+j)*132 + kc4];
            #pragma unroll
            for (int kk = 0; kk < 4; ++kk) {
                const float4 wv = *(const float4*)&W[(size_t)(kc4+kk)*G3];
                #pragma unroll
                for (int j = 0; j < 4; ++j) {
                    const float xj = (kk==0) ? xv[j].x : (kk==1) ? xv[j].y
                                   : (kk==2) ? xv[j].z : xv[j].w;
                    acc[j].x += xj*wv.x; acc[j].y += xj*wv.y;
                    acc[j].z += xj*wv.z; acc[j].w += xj*wv.w;
                }
            }
        }
        #pragma unroll
        for (int j = 0; j < 4; ++j)
            *(float4*)&outp[(size_t)(m0+rb+j)*G3 + n] = acc[j];
    }

    // ---- completion protocol ----
    __threadfence();                              // release partial stores
    __syncthreads();
    const int dx = x & 7;                          // x % 8 (tile within gate)
    const int ci = y*8 + dx;
    if (tid == 0) {
        int old = __hip_atomic_fetch_add(&cnt[ci], 1, __ATOMIC_ACQ_REL,
                                         __HIP_MEMORY_SCOPE_AGENT);
        last = (old == 11);
    }
    __syncthreads();
    if (!last) return;
    if (tid == 0)
        __hip_atomic_store(&cnt[ci], 0, __ATOMIC_RELAXED, __HIP_MEMORY_SCOPE_AGENT);
    __threadfence();                              // acquire before reading partials

    // ---- fused GRU epilogue for tile rows m0..m0+31, d-cols dx*128..+128 ----
    const int d0 = dx*128 + (tid & 31)*4;
    const float4 bir = *(const float4*)&bih[d0];
    const float4 bhr = *(const float4*)&bhh[d0];
    const float4 biz = *(const float4*)&bih[1024+d0];
    const float4 bhz = *(const float4*)&bhh[1024+d0];
    const float4 bin = *(const float4*)&bih[2048+d0];
    const float4 bhn = *(const float4*)&bhh[2048+d0];
    for (int rr = tid >> 5; rr < 32; rr += 8) {
        const int b = m0 + rr;
        float4 gr = make_float4(0.f,0.f,0.f,0.f);
        float4 gz = make_float4(0.f,0.f,0.f,0.f);
        float4 gn = make_float4(0.f,0.f,0.f,0.f);
        #pragma unroll
        for (int c = 0; c < 4; ++c) {
            const float* p = &giP[(size_t)c*393216 + (size_t)b*G3 + d0];
            const float4 a = *(const float4*)&p[0];
            gr.x+=a.x; gr.y+=a.y; gr.z+=a.z; gr.w+=a.w;
            const float4 bb = *(const float4*)&p[1024];
            gz.x+=bb.x; gz.y+=bb.y; gz.z+=bb.z; gz.w+=bb.w;
            const float4 cc = *(const float4*)&p[2048];
            gn.x+=cc.x; gn.y+=cc.y; gn.z+=cc.z; gn.w+=cc.w;
        }
        float4 hr = make_float4(0.f,0.f,0.f,0.f);
        float4 hz = make_float4(0.f,0.f,0.f,0.f);
        float4 hn = make_float4(0.f,0.f,0.f,0.f);
        float4 dold = make_float4(0.f,0.f,0.f,0.f);
        if (have_gh) {
            #pragma unroll
            for (int c = 0; c < 8; ++c) {
                const float* p = &ghP[(size_t)c*393216 + (size_t)b*G3 + d0];
                const float4 a = *(const float4*)&p[0];
                hr.x+=a.x; hr.y+=a.y; hr.z+=a.z; hr.w+=a.w;
                const float4 bb = *(const float4*)&p[1024];
                hz.x+=bb.x; hz.y+=bb.y; hz.z+=bb.z; hz.w+=bb.w;
                const float4 cc = *(const float4*)&p[2048];
                hn.x+=cc.x; hn.y+=cc.y; hn.z+=cc.z; hn.w+=cc.w;
            }
            dold = *(const float4*)&det_in[(size_t)b*ld_det + d0];
        }
        float4 out;
        out.x = gru_out_(gr.x,hr.x,bir.x,bhr.x, gz.x,hz.x,biz.x,bhz.x,
                         gn.x,hn.x,bin.x,bhn.x, dold.x);
        out.y = gru_out_(gr.y,hr.y,bir.y,bhr.y, gz.y,hz.y,biz.y,bhz.y,
                         gn.y,hn.y,bin.y,bhn.y, dold.y);
        out.z = gru_out_(gr.z,hr.z,bir.z,bhr.z, gz.z,hz.z,biz.z,bhz.z,
                         gn.z,hn.z,bin.z,bhn.z, dold.z);
        out.w = gru_out_(gr.w,hr.w,bir.w,bhr.w, gz.w,hz.w,biz.w,bhz.w,
                         gn.w,hn.w,bin.w,bhn.w, dold.w);
        *(float4*)&det_out[(size_t)b*ld_out + d0] = out;
    }
}

// ---------------------------------------------------------------------------
extern "C" void kernel_launch(void* const* d_in, const int* in_sizes, int n_in,
                              void* d_out, int out_size, void* d_ws, size_t ws_size,
                              hipStream_t stream)
{
    const float* obs0 = (const float*)d_in[0];
    const float* obs1 = (const float*)d_in[1];
    const float* obs2 = (const float*)d_in[2];
    const float* Wp   = (const float*)d_in[3];
    const float* bp   = (const float*)d_in[4];
    const float* Wih  = (const float*)d_in[5];
    const float* Whh  = (const float*)d_in[6];
    const float* bih  = (const float*)d_in[7];
    const float* bhh  = (const float*)d_in[8];
    const float* Wq   = (const float*)d_in[9];
    const float* bq   = (const float*)d_in[10];
    const float* Wqm  = (const float*)d_in[11];
    const float* bqm  = (const float*)d_in[12];

    float* ws = (float*)d_ws;
    int*   cnt  = (int*)ws;  ws += 1024;            // 32 counters (+ pad)
    float* WqsA = ws;  ws += (size_t)3*512*512;     // folded Wqm@Wp_s per level
    float* bpsA = ws;  ws += (size_t)3*512;         // folded bias per level
    float* dets2= ws;  ws += (size_t)128*16*1024;
    float* dets1= ws;  ws += (size_t)128*64*1024;
    float* HCu  = ws;  ws += (size_t)128*64*512;    // ctx@Wpc per level (reused)
    float* qp   = ws;  ws += (size_t)6*128*512;     // qh partials (6 K-chunks)
    float* hp   = ws;  ws += (size_t)4*128*512;     // h partials (4 K-chunks)
    float* giP  = ws;  ws += (size_t)4*128*3072;    // gi partials
    float* ghP  = ws;  ws += (size_t)8*128*3072;    // gh partials

    zero_k<<<dim3(1), dim3(256), 0, stream>>>((float*)cnt, 1024);

    // Per-level precompute: Wqs = Wqm @ Wp_s ; bps = bp + bqm @ Wp_s
    for (int l = 0; l < 3; ++l) {
        const float* Wp_l = Wp + (size_t)l*1152*512;
        gemm_k<<<dim3(8,32), dim3(256), 0, stream>>>(
            Wqm + (size_t)l*512*128, 128, Wp_l, 512, nullptr,
            WqsA + (size_t)l*512*512, 512, 128);
        bps_k<<<dim3(1), dim3(512), 0, stream>>>(
            bqm + (size_t)l*128, Wp_l, bp + (size_t)l*512, bpsA + (size_t)l*512);
    }

    const float* obsv[3] = {obs0, obs1, obs2};
    const int Tv[3] = {256, 64, 16};

    for (int level = 2; level >= 0; --level) {
        const int T = Tv[level];
        const float* o = obsv[level];
        float* dseq = (level == 0) ? (float*)d_out : (level == 1 ? dets1 : dets2);
        const float* ctxd = (level == 2) ? nullptr : (level == 1 ? dets2 : dets1);
        const int Tc = (level == 1) ? 16 : 64;

        const float* Wp_l  = Wp  + (size_t)level*1152*512;
        const float* Wpc_l = Wp_l + (size_t)128*512;     // ctx rows of Wp
        const float* bp_l  = bp  + (size_t)level*512;
        const float* Wih_l = Wih + (size_t)level*512*3072;
        const float* Whh_l = Whh + (size_t)level*1024*3072;
        const float* bih_l = bih + (size_t)level*3072;
        const float* bhh_l = bhh + (size_t)level*3072;
        const float* Wq_l  = Wq  + (size_t)level*1536*512;
        const float* bq_l  = bq  + (size_t)level*512;
        const float* Wqs_l = WqsA + (size_t)level*512*512;
        const float* bps_l = bpsA + (size_t)level*512;

        // Hoisted: HCu[(b*Tc+tc)][512] = ctx @ Wpc (previous level's output final)
        if (level < 2) {
            gemm_k<<<dim3(8, (128*Tc)/16), dim3(256), 0, stream>>>(
                ctxd, 1024, Wpc_l, 512, nullptr, HCu, 512, 1024);
        }

        for (int t = 0; t < T; ++t) {
            const float* dprev = t ? dseq + (size_t)(t-1)*1024 : dseq;  // unused t==0
            const long   ldd   = (long)T*1024;
            if (t > 0) {
                stepA_k<<<dim3(1152), dim3(256), 0, stream>>>(
                    dprev, ldd, o + (size_t)(t-1)*512, (long)T*512,
                    Wq_l, qp, Whh_l, ghP);
                h_part_k<<<dim3(4,16,4), dim3(256), 0, stream>>>(qp, bq_l, Wqs_l, hp);
            }
            const float* hc_t = (level < 2) ? HCu + (size_t)(t % Tc)*512 : nullptr;
            stepC_k<<<dim3(24,4,4), dim3(256), 0, stream>>>(
                t ? hp : nullptr, hc_t, (long)Tc*512,
                t ? bps_l : bp_l, dprev, ldd,
                Wih_l, giP, ghP, bih_l, bhh_l,
                dseq + (size_t)t*1024, ldd, t > 0 ? 1 : 0, cnt);
        }
    }
}

// Round 5
// 34527.451 us; speedup vs baseline: 1.1691x; 1.1691x over previous
//
#include <hip/hip_runtime.h>
#include <math.h>
#include <cstddef>

#define G3 3072

__device__ __forceinline__ float sigmoidf_(float x){ return 1.0f/(1.0f+expf(-x)); }

// ---------------------------------------------------------------------------
// C[M x N] = A[M x K] @ B[K x N] (+bias). grid (N/64, M/16), block 256.
// Used for per-level Wqs fold and the per-level HC = ctx @ Wpc precompute.
__global__ __launch_bounds__(256)
void gemm_k(const float* __restrict__ A, long lda,
            const float* __restrict__ Bm, long ldb,
            const float* __restrict__ bias,
            float* __restrict__ C, long ldc, int K)
{
    __shared__ float xs[16][64];
    const int tid = threadIdx.x;
    const int nl = tid & 31, bl = tid >> 5;
    const int n  = blockIdx.x*64 + nl*2;
    const int m0 = blockIdx.y*16;
    float a0x=0.f,a0y=0.f,a1x=0.f,a1y=0.f;
    for (int kc = 0; kc < K; kc += 64) {
        __syncthreads();
        { int r = tid >> 4, c = (tid & 15)*4;
          *(float4*)&xs[r][c] = *(const float4*)&A[(size_t)(m0+r)*lda + kc + c]; }
        __syncthreads();
        #pragma unroll 8
        for (int kk = 0; kk < 64; ++kk) {
            const float2 w = *(const float2*)&Bm[(size_t)(kc+kk)*ldb + n];
            const float xa = xs[bl][kk], xb = xs[bl+8][kk];
            a0x += xa*w.x; a0y += xa*w.y;
            a1x += xb*w.x; a1y += xb*w.y;
        }
    }
    float bx=0.f, by=0.f;
    if (bias){ bx = bias[n]; by = bias[n+1]; }
    float* c0 = &C[(size_t)(m0+bl)*ldc + n];
    float* c1 = &C[(size_t)(m0+bl+8)*ldc + n];
    c0[0]=a0x+bx; c0[1]=a0y+by; c1[0]=a1x+bx; c1[1]=a1y+by;
}

// ---------------------------------------------------------------------------
// bps = bp + bqm @ Wp_s   (Wp_s = first 128 rows of Wp_l). 1 block x 512.
__global__ __launch_bounds__(512)
void bps_k(const float* __restrict__ bqm, const float* __restrict__ Wps,
           const float* __restrict__ bp, float* __restrict__ bps)
{
    const int n = threadIdx.x;
    float a = 0.f;
    #pragma unroll 8
    for (int k = 0; k < 128; ++k) a += bqm[k]*Wps[(size_t)k*512 + n];
    bps[n] = a + bp[n];
}

// ---------------------------------------------------------------------------
// Step stage A (t>0 only): one dispatch computing BOTH
//   blocks [0,384):   qp[cz][128][512] partials of det@Wq[0:1024]+obs@Wq[1024:1536]
//                     decode: x=bid&3, y=(bid>>2)&15, cz=bid>>6 (6 chunks)
//   blocks [384,1152): ghP[zc][128][3072] = det @ Whh K-chunk zc*128
//                     decode: g=bid-384; x=g%24, y=(g/24)&3, zc=g/96 (8)
// (verified round 4)
__global__ __launch_bounds__(256)
void stepA_k(const float* __restrict__ det, long ld_det,   // det_{t-1}
             const float* __restrict__ obs, long ld_obs,   // obs_{t-1}
             const float* __restrict__ Wq,                  // 1536 x 512
             float* __restrict__ qp,                        // 6 x 128 x 512
             const float* __restrict__ Whh,                 // 1024 x 3072
             float* __restrict__ ghP)                       // 8 x 128 x 3072
{
    __shared__ float xs[32*132];
    const int tid = threadIdx.x;
    const int bid = blockIdx.x;
    if (bid < 384) {
        // ---- qp partial GEMM, K=256 per chunk, 4 cols/thread (float4 W) ----
        const int x = bid & 3, y = (bid>>2)&15, cz = bid>>6;
        const int nl = tid & 31, mg = tid >> 5;
        const int n  = x*128 + nl*4;
        const int m0 = y*8;
        const float* As; long lda; int kr0;
        if (cz < 4) { As = det + cz*256;     lda = ld_det; kr0 = cz*256; }
        else        { As = obs + (cz-4)*256; lda = ld_obs; kr0 = 1024 + (cz-4)*256; }
        {   // stage 8 rows x 256 cols
            const int r = tid >> 5, c = (tid & 31)*8;
            const float* src = &As[(size_t)(m0+r)*lda + c];
            *(float4*)&xs[r*256 + c]     = *(const float4*)&src[0];
            *(float4*)&xs[r*256 + c + 4] = *(const float4*)&src[4];
        }
        __syncthreads();
        const float* w = &Wq[(size_t)kr0*512 + n];
        float4 acc = make_float4(0.f,0.f,0.f,0.f);
        #pragma unroll 8
        for (int kk = 0; kk < 256; ++kk) {
            const float4 wv = *(const float4*)&w[(size_t)kk*512];
            const float xv = xs[mg*256 + kk];
            acc.x += xv*wv.x; acc.y += xv*wv.y;
            acc.z += xv*wv.z; acc.w += xv*wv.w;
        }
        *(float4*)&qp[(size_t)cz*65536 + (size_t)(m0+mg)*512 + n] = acc;
    } else {
        // ---- ghP partial GEMM: det @ Whh, 32 rows x 128 cols, K=128 ----
        const int g = bid - 384;
        const int x = g % 24, y = (g/24)&3, zc = g/96;
        const int nl = tid & 31, mg = tid >> 5;
        const int n  = x*128 + nl*4;
        const int m0 = y*32;
        const int kb = zc*128;
        {   // stage A-tile 32 rows x 128 cols
            const int r = tid >> 3, c0 = (tid & 7)*16;
            #pragma unroll
            for (int i = 0; i < 4; ++i) {
                const int c = c0 + i*4;
                *(float4*)&xs[r*132 + c] =
                    *(const float4*)&det[(size_t)(m0+r)*ld_det + kb + c];
            }
        }
        __syncthreads();
        const float* W = Whh + (size_t)kb*G3 + n;
        float* outp = ghP + (size_t)zc*393216;
        float4 acc[4];
        #pragma unroll
        for (int j = 0; j < 4; ++j) acc[j] = make_float4(0.f,0.f,0.f,0.f);
        const int rb = mg*4;
        #pragma unroll 2
        for (int kc4 = 0; kc4 < 128; kc4 += 4) {
            float4 xv[4];
            #pragma unroll
            for (int j = 0; j < 4; ++j)
                xv[j] = *(const float4*)&xs[(rb+j)*132 + kc4];
            #pragma unroll
            for (int kk = 0; kk < 4; ++kk) {
                const float4 wv = *(const float4*)&W[(size_t)(kc4+kk)*G3];
                #pragma unroll
                for (int j = 0; j < 4; ++j) {
                    const float xj = (kk==0) ? xv[j].x : (kk==1) ? xv[j].y
                                   : (kk==2) ? xv[j].z : xv[j].w;
                    acc[j].x += xj*wv.x; acc[j].y += xj*wv.y;
                    acc[j].z += xj*wv.z; acc[j].w += xj*wv.w;
                }
            }
        }
        #pragma unroll
        for (int j = 0; j < 4; ++j)
            *(float4*)&outp[(size_t)(m0+rb+j)*G3 + n] = acc[j];
    }
}

// ---------------------------------------------------------------------------
// hp[kz][128][512] partial of qh @ Wqs, qh = relu(sum qp + bq) built in-stage.
// grid (4, 16, 4), block 256; 4 cols/thread (float4 W). (verified round 4)
__global__ __launch_bounds__(256)
void h_part_k(const float* __restrict__ qp, const float* __restrict__ bq,
              const float* __restrict__ Wqs, float* __restrict__ hp)
{
    __shared__ float xs[8*128];
    const int tid = threadIdx.x;
    const int nl = tid & 31, mg = tid >> 5;
    const int n  = blockIdx.x*128 + nl*4;
    const int m0 = blockIdx.y*8;
    const int kz = blockIdx.z;
    {   // stage: qh[m0..m0+7][kz*128..+127] = relu(sum qp + bq)
        const int r = tid >> 5, c = (tid & 31)*4;
        const int kg = kz*128 + c;
        float4 s = *(const float4*)&bq[kg];
        #pragma unroll
        for (int cc = 0; cc < 6; ++cc) {
            const float4 p = *(const float4*)&qp[(size_t)cc*65536 + (size_t)(m0+r)*512 + kg];
            s.x += p.x; s.y += p.y; s.z += p.z; s.w += p.w;
        }
        s.x = fmaxf(s.x,0.f); s.y = fmaxf(s.y,0.f);
        s.z = fmaxf(s.z,0.f); s.w = fmaxf(s.w,0.f);
        *(float4*)&xs[r*128 + c] = s;
    }
    __syncthreads();
    const float* w = &Wqs[(size_t)(kz*128)*512 + n];
    float4 acc = make_float4(0.f,0.f,0.f,0.f);
    #pragma unroll 8
    for (int kk = 0; kk < 128; ++kk) {
        const float4 wv = *(const float4*)&w[(size_t)kk*512];
        const float xv = xs[mg*128 + kk];
        acc.x += xv*wv.x; acc.y += xv*wv.y;
        acc.z += xv*wv.z; acc.w += xv*wv.w;
    }
    *(float4*)&hp[(size_t)kz*65536 + (size_t)(m0+mg)*512 + n] = acc;
}

// ---------------------------------------------------------------------------
// Step stage C: full-K gi GEMM + inline GRU epilogue. NO cross-block sync:
// each block owns its whole output tile. grid (16,16), block 256.
// Thread: d = bx*64 + (tid&31)*2 (2 cols x 3 gates), row b = by*8 + (tid>>5).
// h = relu(sum_cc hp[cc] + hc_t + hbias) staged to LDS (8 rows x 512).
// gh comes complete from stepA's ghP (ordinary inter-kernel dependency).
__global__ __launch_bounds__(256)
void stepC_k(const float* __restrict__ hp,        // 4x128x512, or null (t==0)
             const float* __restrict__ hc, long ld_hc,  // pre-offset; or null
             const float* __restrict__ hbias,     // bps (t>0) or bp (t==0)
             const float* __restrict__ det_in, long ld_det,   // det_{t-1}
             const float* __restrict__ Wih,       // 512 x 3072
             const float* __restrict__ ghP,       // 8 x 128 x 3072 (from stepA)
             const float* __restrict__ bih, const float* __restrict__ bhh,
             float* __restrict__ det_out, long ld_out,
             int have_gh)
{
    __shared__ float xs[8*512];                    // 16 KB
    const int tid = threadIdx.x;
    const int nl = tid & 31, mg = tid >> 5;
    const int d  = blockIdx.x*64 + nl*2;
    const int b0 = blockIdx.y*8;
    {   // stage h-tile 8 rows x 512 cols in 4 passes
        const int r = tid >> 5, cl = (tid & 31)*4;
        #pragma unroll
        for (int pass = 0; pass < 4; ++pass) {
            const int kg = pass*128 + cl;
            float4 s = *(const float4*)&hbias[kg];
            if (hc) {
                const float4 p = *(const float4*)&hc[(size_t)(b0+r)*ld_hc + kg];
                s.x+=p.x; s.y+=p.y; s.z+=p.z; s.w+=p.w;
            }
            if (hp) {
                #pragma unroll
                for (int cc = 0; cc < 4; ++cc) {
                    const float4 p = *(const float4*)&hp[(size_t)cc*65536 + (size_t)(b0+r)*512 + kg];
                    s.x+=p.x; s.y+=p.y; s.z+=p.z; s.w+=p.w;
                }
            }
            s.x=fmaxf(s.x,0.f); s.y=fmaxf(s.y,0.f);
            s.z=fmaxf(s.z,0.f); s.w=fmaxf(s.w,0.f);
            *(float4*)&xs[r*512 + kg] = s;
        }
    }
    __syncthreads();

    // gi over full K=512 (sequential k, round-0/1-verified accumulation order)
    float2 ar = make_float2(0.f,0.f);
    float2 az = make_float2(0.f,0.f);
    float2 an = make_float2(0.f,0.f);
    const float* Wb = Wih + d;
    #pragma unroll 4
    for (int k = 0; k < 512; ++k) {
        const float xv = xs[mg*512 + k];           // broadcast within half-wave
        const float* w = Wb + (size_t)k*G3;
        const float2 wr = *(const float2*)w;
        const float2 wz = *(const float2*)(w + 1024);
        const float2 wn = *(const float2*)(w + 2048);
        ar.x += xv*wr.x; ar.y += xv*wr.y;
        az.x += xv*wz.x; az.y += xv*wz.y;
        an.x += xv*wn.x; an.y += xv*wn.y;
    }

    // gh reduction (8 chunks, order matches rounds 3/4) + GRU pointwise
    const int b = b0 + mg;
    float2 hr = make_float2(0.f,0.f);
    float2 hz = make_float2(0.f,0.f);
    float2 hn = make_float2(0.f,0.f);
    float2 dold = make_float2(0.f,0.f);
    if (have_gh) {
        #pragma unroll
        for (int c = 0; c < 8; ++c) {
            const float* p = &ghP[(size_t)c*393216 + (size_t)b*G3 + d];
            const float2 a2 = *(const float2*)p;
            hr.x += a2.x; hr.y += a2.y;
            const float2 b2 = *(const float2*)(p + 1024);
            hz.x += b2.x; hz.y += b2.y;
            const float2 c2 = *(const float2*)(p + 2048);
            hn.x += c2.x; hn.y += c2.y;
        }
        dold = *(const float2*)&det_in[(size_t)b*ld_det + d];
    }
    const float2 brI = *(const float2*)&bih[d];
    const float2 brH = *(const float2*)&bhh[d];
    const float2 bzI = *(const float2*)&bih[1024+d];
    const float2 bzH = *(const float2*)&bhh[1024+d];
    const float2 bnI = *(const float2*)&bih[2048+d];
    const float2 bnH = *(const float2*)&bhh[2048+d];

    const float rx = sigmoidf_(ar.x + hr.x + brI.x + brH.x);
    const float ry = sigmoidf_(ar.y + hr.y + brI.y + brH.y);
    const float zx = sigmoidf_(az.x + hz.x + bzI.x + bzH.x);
    const float zy = sigmoidf_(az.y + hz.y + bzI.y + bzH.y);
    const float nx = tanhf(an.x + bnI.x + rx*(hn.x + bnH.x));
    const float ny = tanhf(an.y + bnI.y + ry*(hn.y + bnH.y));
    float2 dn;
    dn.x = (1.f - zx)*nx + zx*dold.x;
    dn.y = (1.f - zy)*ny + zy*dold.y;
    *(float2*)&det_out[(size_t)b*ld_out + d] = dn;
}

// ---------------------------------------------------------------------------
extern "C" void kernel_launch(void* const* d_in, const int* in_sizes, int n_in,
                              void* d_out, int out_size, void* d_ws, size_t ws_size,
                              hipStream_t stream)
{
    const float* obs0 = (const float*)d_in[0];
    const float* obs1 = (const float*)d_in[1];
    const float* obs2 = (const float*)d_in[2];
    const float* Wp   = (const float*)d_in[3];
    const float* bp   = (const float*)d_in[4];
    const float* Wih  = (const float*)d_in[5];
    const float* Whh  = (const float*)d_in[6];
    const float* bih  = (const float*)d_in[7];
    const float* bhh  = (const float*)d_in[8];
    const float* Wq   = (const float*)d_in[9];
    const float* bq   = (const float*)d_in[10];
    const float* Wqm  = (const float*)d_in[11];
    const float* bqm  = (const float*)d_in[12];

    float* ws = (float*)d_ws;
    float* WqsA = ws;  ws += (size_t)3*512*512;     // folded Wqm@Wp_s per level
    float* bpsA = ws;  ws += (size_t)3*512;         // folded bias per level
    float* dets2= ws;  ws += (size_t)128*16*1024;
    float* dets1= ws;  ws += (size_t)128*64*1024;
    float* HCu  = ws;  ws += (size_t)128*64*512;    // ctx@Wpc per level (reused)
    float* qp   = ws;  ws += (size_t)6*128*512;     // qh partials (6 K-chunks)
    float* hp   = ws;  ws += (size_t)4*128*512;     // h partials (4 K-chunks)
    float* ghP  = ws;  ws += (size_t)8*128*3072;    // gh partials

    // Per-level precompute: Wqs = Wqm @ Wp_s ; bps = bp + bqm @ Wp_s
    for (int l = 0; l < 3; ++l) {
        const float* Wp_l = Wp + (size_t)l*1152*512;
        gemm_k<<<dim3(8,32), dim3(256), 0, stream>>>(
            Wqm + (size_t)l*512*128, 128, Wp_l, 512, nullptr,
            WqsA + (size_t)l*512*512, 512, 128);
        bps_k<<<dim3(1), dim3(512), 0, stream>>>(
            bqm + (size_t)l*128, Wp_l, bp + (size_t)l*512, bpsA + (size_t)l*512);
    }

    const float* obsv[3] = {obs0, obs1, obs2};
    const int Tv[3] = {256, 64, 16};

    for (int level = 2; level >= 0; --level) {
        const int T = Tv[level];
        const float* o = obsv[level];
        float* dseq = (level == 0) ? (float*)d_out : (level == 1 ? dets1 : dets2);
        const float* ctxd = (level == 2) ? nullptr : (level == 1 ? dets2 : dets1);
        const int Tc = (level == 1) ? 16 : 64;

        const float* Wp_l  = Wp  + (size_t)level*1152*512;
        const float* Wpc_l = Wp_l + (size_t)128*512;     // ctx rows of Wp
        const float* bp_l  = bp  + (size_t)level*512;
        const float* Wih_l = Wih + (size_t)level*512*3072;
        const float* Whh_l = Whh + (size_t)level*1024*3072;
        const float* bih_l = bih + (size_t)level*3072;
        const float* bhh_l = bhh + (size_t)level*3072;
        const float* Wq_l  = Wq  + (size_t)level*1536*512;
        const float* bq_l  = bq  + (size_t)level*512;
        const float* Wqs_l = WqsA + (size_t)level*512*512;
        const float* bps_l = bpsA + (size_t)level*512;

        // Hoisted: HCu[(b*Tc+tc)][512] = ctx @ Wpc (previous level's output final)
        if (level < 2) {
            gemm_k<<<dim3(8, (128*Tc)/16), dim3(256), 0, stream>>>(
                ctxd, 1024, Wpc_l, 512, nullptr, HCu, 512, 1024);
        }

        for (int t = 0; t < T; ++t) {
            const float* dprev = t ? dseq + (size_t)(t-1)*1024 : dseq;  // unused t==0
            const long   ldd   = (long)T*1024;
            if (t > 0) {
                stepA_k<<<dim3(1152), dim3(256), 0, stream>>>(
                    dprev, ldd, o + (size_t)(t-1)*512, (long)T*512,
                    Wq_l, qp, Whh_l, ghP);
                h_part_k<<<dim3(4,16,4), dim3(256), 0, stream>>>(qp, bq_l, Wqs_l, hp);
            }
            const float* hc_t = (level < 2) ? HCu + (size_t)(t % Tc)*512 : nullptr;
            stepC_k<<<dim3(16,16), dim3(256), 0, stream>>>(
                t ? hp : nullptr, hc_t, (long)Tc*512,
                t ? bps_l : bp_l, dprev, ldd,
                Wih_l, ghP, bih_l, bhh_l,
                dseq + (size_t)t*1024, ldd, t > 0 ? 1 : 0);
        }
    }
}

// Round 6
// 29856.247 us; speedup vs baseline: 1.3520x; 1.1565x over previous
//
#include <hip/hip_runtime.h>
#include <math.h>
#include <cstddef>

#define G3 3072

__device__ __forceinline__ float sigmoidf_(float x){ return 1.0f/(1.0f+expf(-x)); }

// ---------------------------------------------------------------------------
// C[M x N] = A[M x K] @ B[K x N] (+bias). grid (N/64, M/16), block 256.
// Used for per-level Wqs fold and the per-level HC = ctx @ Wpc precompute.
__global__ __launch_bounds__(256)
void gemm_k(const float* __restrict__ A, long lda,
            const float* __restrict__ Bm, long ldb,
            const float* __restrict__ bias,
            float* __restrict__ C, long ldc, int K)
{
    __shared__ float xs[16][64];
    const int tid = threadIdx.x;
    const int nl = tid & 31, bl = tid >> 5;
    const int n  = blockIdx.x*64 + nl*2;
    const int m0 = blockIdx.y*16;
    float a0x=0.f,a0y=0.f,a1x=0.f,a1y=0.f;
    for (int kc = 0; kc < K; kc += 64) {
        __syncthreads();
        { int r = tid >> 4, c = (tid & 15)*4;
          *(float4*)&xs[r][c] = *(const float4*)&A[(size_t)(m0+r)*lda + kc + c]; }
        __syncthreads();
        #pragma unroll 8
        for (int kk = 0; kk < 64; ++kk) {
            const float2 w = *(const float2*)&Bm[(size_t)(kc+kk)*ldb + n];
            const float xa = xs[bl][kk], xb = xs[bl+8][kk];
            a0x += xa*w.x; a0y += xa*w.y;
            a1x += xb*w.x; a1y += xb*w.y;
        }
    }
    float bx=0.f, by=0.f;
    if (bias){ bx = bias[n]; by = bias[n+1]; }
    float* c0 = &C[(size_t)(m0+bl)*ldc + n];
    float* c1 = &C[(size_t)(m0+bl+8)*ldc + n];
    c0[0]=a0x+bx; c0[1]=a0y+by; c1[0]=a1x+bx; c1[1]=a1y+by;
}

// ---------------------------------------------------------------------------
// bps = bp + bqm @ Wp_s   (Wp_s = first 128 rows of Wp_l). 1 block x 512.
__global__ __launch_bounds__(512)
void bps_k(const float* __restrict__ bqm, const float* __restrict__ Wps,
           const float* __restrict__ bp, float* __restrict__ bps)
{
    const int n = threadIdx.x;
    float a = 0.f;
    #pragma unroll 8
    for (int k = 0; k < 128; ++k) a += bqm[k]*Wps[(size_t)k*512 + n];
    bps[n] = a + bp[n];
}

// ---------------------------------------------------------------------------
// Step stage A (t>0 only): one dispatch computing BOTH
//   blocks [0,384):   qp[cz][128][512] partials of det@Wq[0:1024]+obs@Wq[1024:1536]
//   blocks [384,1152): ghP[zc][128][3072] = det @ Whh K-chunk zc*128
// (verified rounds 4/5)
__global__ __launch_bounds__(256)
void stepA_k(const float* __restrict__ det, long ld_det,   // det_{t-1}
             const float* __restrict__ obs, long ld_obs,   // obs_{t-1}
             const float* __restrict__ Wq,                  // 1536 x 512
             float* __restrict__ qp,                        // 6 x 128 x 512
             const float* __restrict__ Whh,                 // 1024 x 3072
             float* __restrict__ ghP)                       // 8 x 128 x 3072
{
    __shared__ float xs[32*132];
    const int tid = threadIdx.x;
    const int bid = blockIdx.x;
    if (bid < 384) {
        // ---- qp partial GEMM, K=256 per chunk, 4 cols/thread (float4 W) ----
        const int x = bid & 3, y = (bid>>2)&15, cz = bid>>6;
        const int nl = tid & 31, mg = tid >> 5;
        const int n  = x*128 + nl*4;
        const int m0 = y*8;
        const float* As; long lda; int kr0;
        if (cz < 4) { As = det + cz*256;     lda = ld_det; kr0 = cz*256; }
        else        { As = obs + (cz-4)*256; lda = ld_obs; kr0 = 1024 + (cz-4)*256; }
        {   // stage 8 rows x 256 cols
            const int r = tid >> 5, c = (tid & 31)*8;
            const float* src = &As[(size_t)(m0+r)*lda + c];
            *(float4*)&xs[r*256 + c]     = *(const float4*)&src[0];
            *(float4*)&xs[r*256 + c + 4] = *(const float4*)&src[4];
        }
        __syncthreads();
        const float* w = &Wq[(size_t)kr0*512 + n];
        float4 acc = make_float4(0.f,0.f,0.f,0.f);
        #pragma unroll 8
        for (int kk = 0; kk < 256; ++kk) {
            const float4 wv = *(const float4*)&w[(size_t)kk*512];
            const float xv = xs[mg*256 + kk];
            acc.x += xv*wv.x; acc.y += xv*wv.y;
            acc.z += xv*wv.z; acc.w += xv*wv.w;
        }
        *(float4*)&qp[(size_t)cz*65536 + (size_t)(m0+mg)*512 + n] = acc;
    } else {
        // ---- ghP partial GEMM: det @ Whh, 32 rows x 128 cols, K=128 ----
        const int g = bid - 384;
        const int x = g % 24, y = (g/24)&3, zc = g/96;
        const int nl = tid & 31, mg = tid >> 5;
        const int n  = x*128 + nl*4;
        const int m0 = y*32;
        const int kb = zc*128;
        {   // stage A-tile 32 rows x 128 cols
            const int r = tid >> 3, c0 = (tid & 7)*16;
            #pragma unroll
            for (int i = 0; i < 4; ++i) {
                const int c = c0 + i*4;
                *(float4*)&xs[r*132 + c] =
                    *(const float4*)&det[(size_t)(m0+r)*ld_det + kb + c];
            }
        }
        __syncthreads();
        const float* W = Whh + (size_t)kb*G3 + n;
        float* outp = ghP + (size_t)zc*393216;
        float4 acc[4];
        #pragma unroll
        for (int j = 0; j < 4; ++j) acc[j] = make_float4(0.f,0.f,0.f,0.f);
        const int rb = mg*4;
        #pragma unroll 2
        for (int kc4 = 0; kc4 < 128; kc4 += 4) {
            float4 xv[4];
            #pragma unroll
            for (int j = 0; j < 4; ++j)
                xv[j] = *(const float4*)&xs[(rb+j)*132 + kc4];
            #pragma unroll
            for (int kk = 0; kk < 4; ++kk) {
                const float4 wv = *(const float4*)&W[(size_t)(kc4+kk)*G3];
                #pragma unroll
                for (int j = 0; j < 4; ++j) {
                    const float xj = (kk==0) ? xv[j].x : (kk==1) ? xv[j].y
                                   : (kk==2) ? xv[j].z : xv[j].w;
                    acc[j].x += xj*wv.x; acc[j].y += xj*wv.y;
                    acc[j].z += xj*wv.z; acc[j].w += xj*wv.w;
                }
            }
        }
        #pragma unroll
        for (int j = 0; j < 4; ++j)
            *(float4*)&outp[(size_t)(m0+rb+j)*G3 + n] = acc[j];
    }
}

// ---------------------------------------------------------------------------
// hp[kz][128][512] partial of qh @ Wqs, qh = relu(sum qp + bq) built in-stage.
// grid (4, 16, 4), block 256; 4 cols/thread (float4 W). (verified rounds 4/5)
__global__ __launch_bounds__(256)
void h_part_k(const float* __restrict__ qp, const float* __restrict__ bq,
              const float* __restrict__ Wqs, float* __restrict__ hp)
{
    __shared__ float xs[8*128];
    const int tid = threadIdx.x;
    const int nl = tid & 31, mg = tid >> 5;
    const int n  = blockIdx.x*128 + nl*4;
    const int m0 = blockIdx.y*8;
    const int kz = blockIdx.z;
    {   // stage: qh[m0..m0+7][kz*128..+127] = relu(sum qp + bq)
        const int r = tid >> 5, c = (tid & 31)*4;
        const int kg = kz*128 + c;
        float4 s = *(const float4*)&bq[kg];
        #pragma unroll
        for (int cc = 0; cc < 6; ++cc) {
            const float4 p = *(const float4*)&qp[(size_t)cc*65536 + (size_t)(m0+r)*512 + kg];
            s.x += p.x; s.y += p.y; s.z += p.z; s.w += p.w;
        }
        s.x = fmaxf(s.x,0.f); s.y = fmaxf(s.y,0.f);
        s.z = fmaxf(s.z,0.f); s.w = fmaxf(s.w,0.f);
        *(float4*)&xs[r*128 + c] = s;
    }
    __syncthreads();
    const float* w = &Wqs[(size_t)(kz*128)*512 + n];
    float4 acc = make_float4(0.f,0.f,0.f,0.f);
    #pragma unroll 8
    for (int kk = 0; kk < 128; ++kk) {
        const float4 wv = *(const float4*)&w[(size_t)kk*512];
        const float xv = xs[mg*128 + kk];
        acc.x += xv*wv.x; acc.y += xv*wv.y;
        acc.z += xv*wv.z; acc.w += xv*wv.w;
    }
    *(float4*)&hp[(size_t)kz*65536 + (size_t)(m0+mg)*512 + n] = acc;
}

// ---------------------------------------------------------------------------
// Step stage C: gi GEMM with K split ACROSS WAVES + LDS reduce + inline GRU
// epilogue. grid (16,16), block 1024 (16 waves): x = d-tile (64 of 1024),
// y = row-tile (8 of 128). Wave wid: g = wid%3 (gate), kq = wid/3 (K-quarter);
// wid >= 12 idles through barriers. Per lane: 1 col, 8 row-accumulators.
// Accumulation order = R3/R4 (4 sequential K-chunks summed ascending).
__global__ __launch_bounds__(1024)
void stepC_k(const float* __restrict__ hp,        // 4x128x512, or null (t==0)
             const float* __restrict__ hc, long ld_hc,  // pre-offset; or null
             const float* __restrict__ hbias,     // bps (t>0) or bp (t==0)
             const float* __restrict__ det_in, long ld_det,   // det_{t-1}
             const float* __restrict__ Wih,       // 512 x 3072
             const float* __restrict__ ghP,       // 8 x 128 x 3072 (from stepA)
             const float* __restrict__ bih, const float* __restrict__ bhh,
             float* __restrict__ det_out, long ld_out,
             int have_gh)
{
    __shared__ float hs[8*512];                    // 16 KB: h-tile
    __shared__ float ps[12*8*64];                  // 24 KB: per-wave partials
    const int tid  = threadIdx.x;
    const int lane = tid & 63, wid = tid >> 6;
    const int dx   = blockIdx.x;                   // 16 d-tiles of 64
    const int b0   = blockIdx.y*8;                 // 16 row-tiles of 8

    {   // stage h-tile 8 rows x 512 cols: relu(sum hp + hc + bias), one pass
        const int r = tid >> 7, c = (tid & 127)*4;
        float4 s = *(const float4*)&hbias[c];
        if (hc) {
            const float4 p = *(const float4*)&hc[(size_t)(b0+r)*ld_hc + c];
            s.x+=p.x; s.y+=p.y; s.z+=p.z; s.w+=p.w;
        }
        if (hp) {
            #pragma unroll
            for (int cc = 0; cc < 4; ++cc) {
                const float4 p = *(const float4*)&hp[(size_t)cc*65536 + (size_t)(b0+r)*512 + c];
                s.x+=p.x; s.y+=p.y; s.z+=p.z; s.w+=p.w;
            }
        }
        s.x=fmaxf(s.x,0.f); s.y=fmaxf(s.y,0.f);
        s.z=fmaxf(s.z,0.f); s.w=fmaxf(s.w,0.f);
        *(float4*)&hs[r*512 + c] = s;
    }
    __syncthreads();

    if (wid < 12) {   // gi partial: gate g, K-quarter kq, 8 rows x 64 cols
        const int g = wid % 3, kq = wid / 3;
        const float* Wb = Wih + (size_t)(kq*128)*G3 + g*1024 + dx*64 + lane;
        float acc[8];
        #pragma unroll
        for (int r = 0; r < 8; ++r) acc[r] = 0.f;
        const float* hq = hs + kq*128;
        #pragma unroll 4
        for (int kk = 0; kk < 128; kk += 4) {
            const float w0 = Wb[(size_t)(kk+0)*G3];
            const float w1 = Wb[(size_t)(kk+1)*G3];
            const float w2 = Wb[(size_t)(kk+2)*G3];
            const float w3 = Wb[(size_t)(kk+3)*G3];
            #pragma unroll
            for (int r = 0; r < 8; ++r) {
                const float4 hv = *(const float4*)&hq[r*512 + kk];  // broadcast
                acc[r] += hv.x*w0; acc[r] += hv.y*w1;
                acc[r] += hv.z*w2; acc[r] += hv.w*w3;
            }
        }
        float* pw = &ps[(size_t)wid*512];          // wid = g*4+kq? no: wid=kq*3+g
        #pragma unroll
        for (int r = 0; r < 8; ++r) pw[r*64 + lane] = acc[r];
    }
    __syncthreads();

    if (wid < 8) {     // epilogue: wave = row r, lane = d-col
        const int r = wid;
        const int b = b0 + r;
        const int d = dx*64 + lane;
        // sum 4 K-quarters per gate, ascending (R3/R4 epi order).
        // partial for (g,kq) lives at wave wid=kq*3+g.
        float gi_r=0.f, gi_z=0.f, gi_n=0.f;
        #pragma unroll
        for (int kq = 0; kq < 4; ++kq) {
            gi_r += ps[(size_t)(kq*3+0)*512 + r*64 + lane];
            gi_z += ps[(size_t)(kq*3+1)*512 + r*64 + lane];
            gi_n += ps[(size_t)(kq*3+2)*512 + r*64 + lane];
        }
        float hr=0.f, hz=0.f, hn=0.f, dold=0.f;
        if (have_gh) {
            #pragma unroll
            for (int c = 0; c < 8; ++c) {
                const float* p = &ghP[(size_t)c*393216 + (size_t)b*G3 + d];
                hr += p[0]; hz += p[1024]; hn += p[2048];
            }
            dold = det_in[(size_t)b*ld_det + d];
        }
        const float rr = sigmoidf_(gi_r + hr + bih[d] + bhh[d]);
        const float zz = sigmoidf_(gi_z + hz + bih[1024+d] + bhh[1024+d]);
        const float nn = tanhf(gi_n + bih[2048+d] + rr*(hn + bhh[2048+d]));
        det_out[(size_t)b*ld_out + d] = (1.f - zz)*nn + zz*dold;
    }
}

// ---------------------------------------------------------------------------
extern "C" void kernel_launch(void* const* d_in, const int* in_sizes, int n_in,
                              void* d_out, int out_size, void* d_ws, size_t ws_size,
                              hipStream_t stream)
{
    const float* obs0 = (const float*)d_in[0];
    const float* obs1 = (const float*)d_in[1];
    const float* obs2 = (const float*)d_in[2];
    const float* Wp   = (const float*)d_in[3];
    const float* bp   = (const float*)d_in[4];
    const float* Wih  = (const float*)d_in[5];
    const float* Whh  = (const float*)d_in[6];
    const float* bih  = (const float*)d_in[7];
    const float* bhh  = (const float*)d_in[8];
    const float* Wq   = (const float*)d_in[9];
    const float* bq   = (const float*)d_in[10];
    const float* Wqm  = (const float*)d_in[11];
    const float* bqm  = (const float*)d_in[12];

    float* ws = (float*)d_ws;
    float* WqsA = ws;  ws += (size_t)3*512*512;     // folded Wqm@Wp_s per level
    float* bpsA = ws;  ws += (size_t)3*512;         // folded bias per level
    float* dets2= ws;  ws += (size_t)128*16*1024;
    float* dets1= ws;  ws += (size_t)128*64*1024;
    float* HCu  = ws;  ws += (size_t)128*64*512;    // ctx@Wpc per level (reused)
    float* qp   = ws;  ws += (size_t)6*128*512;     // qh partials (6 K-chunks)
    float* hp   = ws;  ws += (size_t)4*128*512;     // h partials (4 K-chunks)
    float* ghP  = ws;  ws += (size_t)8*128*3072;    // gh partials

    // Per-level precompute: Wqs = Wqm @ Wp_s ; bps = bp + bqm @ Wp_s
    for (int l = 0; l < 3; ++l) {
        const float* Wp_l = Wp + (size_t)l*1152*512;
        gemm_k<<<dim3(8,32), dim3(256), 0, stream>>>(
            Wqm + (size_t)l*512*128, 128, Wp_l, 512, nullptr,
            WqsA + (size_t)l*512*512, 512, 128);
        bps_k<<<dim3(1), dim3(512), 0, stream>>>(
            bqm + (size_t)l*128, Wp_l, bp + (size_t)l*512, bpsA + (size_t)l*512);
    }

    const float* obsv[3] = {obs0, obs1, obs2};
    const int Tv[3] = {256, 64, 16};

    for (int level = 2; level >= 0; --level) {
        const int T = Tv[level];
        const float* o = obsv[level];
        float* dseq = (level == 0) ? (float*)d_out : (level == 1 ? dets1 : dets2);
        const float* ctxd = (level == 2) ? nullptr : (level == 1 ? dets2 : dets1);
        const int Tc = (level == 1) ? 16 : 64;

        const float* Wp_l  = Wp  + (size_t)level*1152*512;
        const float* Wpc_l = Wp_l + (size_t)128*512;     // ctx rows of Wp
        const float* bp_l  = bp  + (size_t)level*512;
        const float* Wih_l = Wih + (size_t)level*512*3072;
        const float* Whh_l = Whh + (size_t)level*1024*3072;
        const float* bih_l = bih + (size_t)level*3072;
        const float* bhh_l = bhh + (size_t)level*3072;
        const float* Wq_l  = Wq  + (size_t)level*1536*512;
        const float* bq_l  = bq  + (size_t)level*512;
        const float* Wqs_l = WqsA + (size_t)level*512*512;
        const float* bps_l = bpsA + (size_t)level*512;

        // Hoisted: HCu[(b*Tc+tc)][512] = ctx @ Wpc (previous level's output final)
        if (level < 2) {
            gemm_k<<<dim3(8, (128*Tc)/16), dim3(256), 0, stream>>>(
                ctxd, 1024, Wpc_l, 512, nullptr, HCu, 512, 1024);
        }

        for (int t = 0; t < T; ++t) {
            const float* dprev = t ? dseq + (size_t)(t-1)*1024 : dseq;  // unused t==0
            const long   ldd   = (long)T*1024;
            if (t > 0) {
                stepA_k<<<dim3(1152), dim3(256), 0, stream>>>(
                    dprev, ldd, o + (size_t)(t-1)*512, (long)T*512,
                    Wq_l, qp, Whh_l, ghP);
                h_part_k<<<dim3(4,16,4), dim3(256), 0, stream>>>(qp, bq_l, Wqs_l, hp);
            }
            const float* hc_t = (level < 2) ? HCu + (size_t)(t % Tc)*512 : nullptr;
            stepC_k<<<dim3(16,16), dim3(1024), 0, stream>>>(
                t ? hp : nullptr, hc_t, (long)Tc*512,
                t ? bps_l : bp_l, dprev, ldd,
                Wih_l, ghP, bih_l, bhh_l,
                dseq + (size_t)t*1024, ldd, t > 0 ? 1 : 0);
        }
    }
}

// Round 7
// 24522.374 us; speedup vs baseline: 1.6460x; 1.2175x over previous
//
#include <hip/hip_runtime.h>
#include <math.h>
#include <cstddef>

#define G3 3072

__device__ __forceinline__ float sigmoidf_(float x){ return 1.0f/(1.0f+expf(-x)); }

// ---------------------------------------------------------------------------
__global__ __launch_bounds__(256)
void zero_k(float* p, int n){
    int i = blockIdx.x*blockDim.x + threadIdx.x;
    for (int j = i; j < n; j += gridDim.x*blockDim.x) p[j] = 0.f;
}

// ---------------------------------------------------------------------------
// C[M x N] = A[M x K] @ B[K x N] (+bias). grid (N/64, M/16), block 256.
// Used for per-level Wqs fold and the per-level HC = ctx @ Wpc precompute.
__global__ __launch_bounds__(256)
void gemm_k(const float* __restrict__ A, long lda,
            const float* __restrict__ Bm, long ldb,
            const float* __restrict__ bias,
            float* __restrict__ C, long ldc, int K)
{
    __shared__ float xs[16][64];
    const int tid = threadIdx.x;
    const int nl = tid & 31, bl = tid >> 5;
    const int n  = blockIdx.x*64 + nl*2;
    const int m0 = blockIdx.y*16;
    float a0x=0.f,a0y=0.f,a1x=0.f,a1y=0.f;
    for (int kc = 0; kc < K; kc += 64) {
        __syncthreads();
        { int r = tid >> 4, c = (tid & 15)*4;
          *(float4*)&xs[r][c] = *(const float4*)&A[(size_t)(m0+r)*lda + kc + c]; }
        __syncthreads();
        #pragma unroll 8
        for (int kk = 0; kk < 64; ++kk) {
            const float2 w = *(const float2*)&Bm[(size_t)(kc+kk)*ldb + n];
            const float xa = xs[bl][kk], xb = xs[bl+8][kk];
            a0x += xa*w.x; a0y += xa*w.y;
            a1x += xb*w.x; a1y += xb*w.y;
        }
    }
    float bx=0.f, by=0.f;
    if (bias){ bx = bias[n]; by = bias[n+1]; }
    float* c0 = &C[(size_t)(m0+bl)*ldc + n];
    float* c1 = &C[(size_t)(m0+bl+8)*ldc + n];
    c0[0]=a0x+bx; c0[1]=a0y+by; c1[0]=a1x+bx; c1[1]=a1y+by;
}

// ---------------------------------------------------------------------------
// bps = bp + bqm @ Wp_s   (Wp_s = first 128 rows of Wp_l). 1 block x 512.
__global__ __launch_bounds__(512)
void bps_k(const float* __restrict__ bqm, const float* __restrict__ Wps,
           const float* __restrict__ bp, float* __restrict__ bps)
{
    const int n = threadIdx.x;
    float a = 0.f;
    #pragma unroll 8
    for (int k = 0; k < 128; ++k) a += bqm[k]*Wps[(size_t)k*512 + n];
    bps[n] = a + bp[n];
}

// ---------------------------------------------------------------------------
// qp[cz][128][512] partial of (det @ Wq[0:1024] + obs @ Wq[1024:1536]).
// cz 0..3 -> det K-chunk cz*256 ; cz 4..5 -> obs K-chunk (cz-4)*256.
// grid (8, 16, 6), block 256.  (byte-identical to R3-verified version)
__global__ __launch_bounds__(256)
void qh_part_k(const float* __restrict__ det, long ld_det,   // pre-offset, step t-1
               const float* __restrict__ obs, long ld_obs,   // pre-offset, step t-1
               const float* __restrict__ Wq,                  // 1536 x 512
               float* __restrict__ qp)                        // 6 x 128 x 512
{
    __shared__ float xs[8][256];
    const int tid = threadIdx.x;
    const int nl = tid & 31, mg = tid >> 5;
    const int n  = blockIdx.x*64 + nl*2;
    const int m0 = blockIdx.y*8;
    const int cz = blockIdx.z;
    const float* As; long lda; int kr0;
    if (cz < 4) { As = det + cz*256;     lda = ld_det; kr0 = cz*256; }
    else        { As = obs + (cz-4)*256; lda = ld_obs; kr0 = 1024 + (cz-4)*256; }
    {   // stage A-tile 8 rows x 256 cols
        const int r = tid >> 5, c = (tid & 31)*8;
        const float* src = &As[(size_t)(m0+r)*lda + c];
        *(float4*)&xs[r][c]   = *(const float4*)&src[0];
        *(float4*)&xs[r][c+4] = *(const float4*)&src[4];
    }
    __syncthreads();
    const float* w = &Wq[(size_t)kr0*512 + n];
    float ax=0.f, ay=0.f;
    #pragma unroll 8
    for (int kk = 0; kk < 256; ++kk) {
        const float2 wv = *(const float2*)&w[(size_t)kk*512];
        const float x = xs[mg][kk];
        ax += x*wv.x; ay += x*wv.y;
    }
    *(float2*)&qp[(size_t)cz*65536 + (size_t)(m0+mg)*512 + n] = make_float2(ax, ay);
}

// ---------------------------------------------------------------------------
// hp[kz][128][512] partial of qh @ Wqs, where qh = relu(sum_c qp[c] + bq)
// is materialized during the A-stage. grid (8, 16, 4), block 256.
// (byte-identical to R3-verified version)
__global__ __launch_bounds__(256)
void h_part_k(const float* __restrict__ qp, const float* __restrict__ bq,
              const float* __restrict__ Wqs, float* __restrict__ hp)
{
    __shared__ float xs[8][128];
    const int tid = threadIdx.x;
    const int nl = tid & 31, mg = tid >> 5;
    const int n  = blockIdx.x*64 + nl*2;
    const int m0 = blockIdx.y*8;
    const int kz = blockIdx.z;
    {   // stage: qh[m0..m0+7][kz*128 .. +127] = relu(sum qp + bq)
        const int r = tid >> 5, c = (tid & 31)*4;
        const int kg = kz*128 + c;
        float4 s = *(const float4*)&bq[kg];
        #pragma unroll
        for (int cc = 0; cc < 6; ++cc) {
            const float4 p = *(const float4*)&qp[(size_t)cc*65536 + (size_t)(m0+r)*512 + kg];
            s.x += p.x; s.y += p.y; s.z += p.z; s.w += p.w;
        }
        s.x = fmaxf(s.x,0.f); s.y = fmaxf(s.y,0.f);
        s.z = fmaxf(s.z,0.f); s.w = fmaxf(s.w,0.f);
        *(float4*)&xs[r][c] = s;
    }
    __syncthreads();
    const float* w = &Wqs[(size_t)(kz*128)*512 + n];
    float ax=0.f, ay=0.f;
    #pragma unroll 8
    for (int kk = 0; kk < 128; ++kk) {
        const float2 wv = *(const float2*)&w[(size_t)kk*512];
        const float x = xs[mg][kk];
        ax += x*wv.x; ay += x*wv.y;
    }
    *(float2*)&hp[(size_t)kz*65536 + (size_t)(m0+mg)*512 + n] = make_float2(ax, ay);
}

// ---------------------------------------------------------------------------
// GRU partial GEMMs, K-chunks of 256 (halves partial-buffer traffic vs R3).
//   zc<2 : giP[zc] = (h-tile) @ Wih K-chunk zc*256, h built in A-stage
//   zc>=2: ghP[zc-2] = det @ Whh K-chunk (zc-2)*256
// grid (24, 4, 6), block 256. Thread: 4 rows x 4 cols; kk unrolled x4 so
// LDS activations load as ds_read_b128 (broadcast) and weights as dwordx4.
__global__ __launch_bounds__(256)
void gru_part_k(const float* __restrict__ hp,       // 4x128x512, or null (t==0)
                const float* __restrict__ hc, long ld_hc,  // pre-offset; or null
                const float* __restrict__ hbias,    // bps (t>0) or bp (t==0)
                const float* __restrict__ det, long ld_det,
                const float* __restrict__ Wih, const float* __restrict__ Whh,
                float* __restrict__ giP, float* __restrict__ ghP)
{
    __shared__ float xs[32*260];                     // 33.3 KB (stride 260: pad)
    const int tid = threadIdx.x;
    const int nl = tid & 31, mg = tid >> 5;
    const int n  = blockIdx.x*128 + nl*4;            // 24 x-blocks cover 3072
    const int m0 = blockIdx.y*32;                    // 4 y-blocks cover 128 rows
    const int zc = blockIdx.z;
    const bool is_gi = (zc < 2);
    {   // stage A-tile 32 rows x 256 cols: r = tid>>3, 8 thr x 32 cols each
        const int r = tid >> 3, c0 = (tid & 7)*32;
        if (is_gi) {
            const int kb = zc*256;
            #pragma unroll
            for (int i = 0; i < 8; ++i) {
                const int c = c0 + i*4, kg = kb + c;
                float4 s = *(const float4*)&hbias[kg];
                if (hc) {
                    const float4 p = *(const float4*)&hc[(size_t)(m0+r)*ld_hc + kg];
                    s.x+=p.x; s.y+=p.y; s.z+=p.z; s.w+=p.w;
                }
                if (hp) {
                    #pragma unroll
                    for (int cc = 0; cc < 4; ++cc) {
                        const float4 p = *(const float4*)&hp[(size_t)cc*65536 + (size_t)(m0+r)*512 + kg];
                        s.x+=p.x; s.y+=p.y; s.z+=p.z; s.w+=p.w;
                    }
                }
                s.x=fmaxf(s.x,0.f); s.y=fmaxf(s.y,0.f);
                s.z=fmaxf(s.z,0.f); s.w=fmaxf(s.w,0.f);
                *(float4*)&xs[r*260 + c] = s;
            }
        } else {
            const int kb = (zc-2)*256;
            #pragma unroll
            for (int i = 0; i < 8; ++i) {
                const int c = c0 + i*4;
                *(float4*)&xs[r*260 + c] =
                    *(const float4*)&det[(size_t)(m0+r)*ld_det + kb + c];
            }
        }
    }
    __syncthreads();
    const float* W; float* outp;
    if (is_gi) { W = Wih + (size_t)(zc*256)*G3 + n;     outp = giP + (size_t)zc*393216; }
    else       { W = Whh + (size_t)((zc-2)*256)*G3 + n; outp = ghP + (size_t)(zc-2)*393216; }
    float4 acc[4];
    #pragma unroll
    for (int j = 0; j < 4; ++j) acc[j] = make_float4(0.f,0.f,0.f,0.f);
    const int rb = mg*4;                             // 4 rows per thread
    #pragma unroll 2
    for (int kc4 = 0; kc4 < 256; kc4 += 4) {
        float4 xv[4];
        #pragma unroll
        for (int j = 0; j < 4; ++j)
            xv[j] = *(const float4*)&xs[(rb+j)*260 + kc4];   // b128, lane-broadcast
        #pragma unroll
        for (int kk = 0; kk < 4; ++kk) {
            const float4 wv = *(const float4*)&W[(size_t)(kc4+kk)*G3];
            #pragma unroll
            for (int j = 0; j < 4; ++j) {
                const float xj = (kk==0) ? xv[j].x : (kk==1) ? xv[j].y
                               : (kk==2) ? xv[j].z : xv[j].w;
                acc[j].x += xj*wv.x; acc[j].y += xj*wv.y;
                acc[j].z += xj*wv.z; acc[j].w += xj*wv.w;
            }
        }
    }
    #pragma unroll
    for (int j = 0; j < 4; ++j)
        *(float4*)&outp[(size_t)(m0+rb+j)*G3 + n] = acc[j];
}

// ---------------------------------------------------------------------------
// GRU pointwise from partials (2 gi + 4 gh chunks). grid (4, 128), block 256.
__global__ __launch_bounds__(256)
void gru_epi_k(const float* __restrict__ giP, const float* __restrict__ ghP,
               const float* __restrict__ bih, const float* __restrict__ bhh,
               const float* __restrict__ det_in, long ld_det,
               float* __restrict__ det_out, long ld_out)
{
    const int d = blockIdx.x*256 + threadIdx.x;
    const int b = blockIdx.y;
    float gir=0.f, giz=0.f, gin=0.f;
    #pragma unroll
    for (int c = 0; c < 2; ++c) {
        const float* p = &giP[(size_t)c*393216 + (size_t)b*G3 + d];
        gir += p[0]; giz += p[1024]; gin += p[2048];
    }
    float ghr=0.f, ghz=0.f, ghn=0.f;
    #pragma unroll
    for (int c = 0; c < 4; ++c) {
        const float* p = &ghP[(size_t)c*393216 + (size_t)b*G3 + d];
        ghr += p[0]; ghz += p[1024]; ghn += p[2048];
    }
    const float r  = sigmoidf_(gir + ghr + bih[d] + bhh[d]);
    const float z  = sigmoidf_(giz + ghz + bih[1024+d] + bhh[1024+d]);
    const float nn = tanhf(gin + bih[2048+d] + r*(ghn + bhh[2048+d]));
    const float dold = det_in[(size_t)b*ld_det + d];
    det_out[(size_t)b*ld_out + d] = (1.f - z)*nn + z*dold;
}

// ---------------------------------------------------------------------------
extern "C" void kernel_launch(void* const* d_in, const int* in_sizes, int n_in,
                              void* d_out, int out_size, void* d_ws, size_t ws_size,
                              hipStream_t stream)
{
    const float* obs0 = (const float*)d_in[0];
    const float* obs1 = (const float*)d_in[1];
    const float* obs2 = (const float*)d_in[2];
    const float* Wp   = (const float*)d_in[3];
    const float* bp   = (const float*)d_in[4];
    const float* Wih  = (const float*)d_in[5];
    const float* Whh  = (const float*)d_in[6];
    const float* bih  = (const float*)d_in[7];
    const float* bhh  = (const float*)d_in[8];
    const float* Wq   = (const float*)d_in[9];
    const float* bq   = (const float*)d_in[10];
    const float* Wqm  = (const float*)d_in[11];
    const float* bqm  = (const float*)d_in[12];

    float* ws = (float*)d_ws;
    float* det0 = ws;  ws += (size_t)128*1024;      // zero initial state
    float* WqsA = ws;  ws += (size_t)3*512*512;     // folded Wqm@Wp_s per level
    float* bpsA = ws;  ws += (size_t)3*512;         // folded bias per level
    float* dets2= ws;  ws += (size_t)128*16*1024;
    float* dets1= ws;  ws += (size_t)128*64*1024;
    float* HCu  = ws;  ws += (size_t)128*64*512;    // ctx@Wpc per level (reused)
    float* qp   = ws;  ws += (size_t)6*128*512;     // qh partials (6 K-chunks)
    float* hp   = ws;  ws += (size_t)4*128*512;     // h partials (4 K-chunks)
    float* giP  = ws;  ws += (size_t)2*128*3072;    // gi partials (2 K-chunks)
    float* ghP  = ws;  ws += (size_t)4*128*3072;    // gh partials (4 K-chunks)

    zero_k<<<dim3(128), dim3(256), 0, stream>>>(det0, 128*1024);

    // Per-level precompute: Wqs = Wqm @ Wp_s ; bps = bp + bqm @ Wp_s
    for (int l = 0; l < 3; ++l) {
        const float* Wp_l = Wp + (size_t)l*1152*512;
        gemm_k<<<dim3(8,32), dim3(256), 0, stream>>>(
            Wqm + (size_t)l*512*128, 128, Wp_l, 512, nullptr,
            WqsA + (size_t)l*512*512, 512, 128);
        bps_k<<<dim3(1), dim3(512), 0, stream>>>(
            bqm + (size_t)l*128, Wp_l, bp + (size_t)l*512, bpsA + (size_t)l*512);
    }

    const float* obsv[3] = {obs0, obs1, obs2};
    const int Tv[3] = {256, 64, 16};

    for (int level = 2; level >= 0; --level) {
        const int T = Tv[level];
        const float* o = obsv[level];
        float* dseq = (level == 0) ? (float*)d_out : (level == 1 ? dets1 : dets2);
        const float* ctxd = (level == 2) ? nullptr : (level == 1 ? dets2 : dets1);
        const int Tc = (level == 1) ? 16 : 64;

        const float* Wp_l  = Wp  + (size_t)level*1152*512;
        const float* Wpc_l = Wp_l + (size_t)128*512;     // ctx rows of Wp
        const float* bp_l  = bp  + (size_t)level*512;
        const float* Wih_l = Wih + (size_t)level*512*3072;
        const float* Whh_l = Whh + (size_t)level*1024*3072;
        const float* bih_l = bih + (size_t)level*3072;
        const float* bhh_l = bhh + (size_t)level*3072;
        const float* Wq_l  = Wq  + (size_t)level*1536*512;
        const float* bq_l  = bq  + (size_t)level*512;
        const float* Wqs_l = WqsA + (size_t)level*512*512;
        const float* bps_l = bpsA + (size_t)level*512;

        // Hoisted: HCu[(b*Tc+tc)][512] = ctx @ Wpc (previous level's output final)
        if (level < 2) {
            gemm_k<<<dim3(8, (128*Tc)/16), dim3(256), 0, stream>>>(
                ctxd, 1024, Wpc_l, 512, nullptr, HCu, 512, 1024);
        }

        for (int t = 0; t < T; ++t) {
            if (t > 0) {
                qh_part_k<<<dim3(8,16,6), dim3(256), 0, stream>>>(
                    dseq + (size_t)(t-1)*1024, (long)T*1024,
                    o + (size_t)(t-1)*512,  (long)T*512, Wq_l, qp);
                h_part_k<<<dim3(8,16,4), dim3(256), 0, stream>>>(qp, bq_l, Wqs_l, hp);
            }
            const float* hc_t  = (level < 2) ? HCu + (size_t)(t % Tc)*512 : nullptr;
            const float* dprev = t ? dseq + (size_t)(t-1)*1024 : det0;
            const long   ldprev = t ? (long)T*1024 : 1024L;
            gru_part_k<<<dim3(24,4,6), dim3(256), 0, stream>>>(
                t ? hp : nullptr, hc_t, (long)Tc*512,
                t ? bps_l : bp_l, dprev, ldprev,
                Wih_l, Whh_l, giP, ghP);
            gru_epi_k<<<dim3(4,128), dim3(256), 0, stream>>>(
                giP, ghP, bih_l, bhh_l, dprev, ldprev,
                dseq + (size_t)t*1024, (long)T*1024);
        }
    }
}

// Round 8
// 24175.484 us; speedup vs baseline: 1.6697x; 1.0143x over previous
//
#include <hip/hip_runtime.h>
#include <math.h>
#include <cstddef>

#define G3 3072

__device__ __forceinline__ float sigmoidf_(float x){ return 1.0f/(1.0f+expf(-x)); }

// ---------------------------------------------------------------------------
__global__ __launch_bounds__(256)
void zero_k(float* p, int n){
    int i = blockIdx.x*blockDim.x + threadIdx.x;
    for (int j = i; j < n; j += gridDim.x*blockDim.x) p[j] = 0.f;
}

// ---------------------------------------------------------------------------
// C[M x N] = A[M x K] @ B[K x N] (+bias). grid (N/64, M/16), block 256.
// Used for per-level Wqs fold and the per-level HC = ctx @ Wpc precompute.
__global__ __launch_bounds__(256)
void gemm_k(const float* __restrict__ A, long lda,
            const float* __restrict__ Bm, long ldb,
            const float* __restrict__ bias,
            float* __restrict__ C, long ldc, int K)
{
    __shared__ float xs[16][64];
    const int tid = threadIdx.x;
    const int nl = tid & 31, bl = tid >> 5;
    const int n  = blockIdx.x*64 + nl*2;
    const int m0 = blockIdx.y*16;
    float a0x=0.f,a0y=0.f,a1x=0.f,a1y=0.f;
    for (int kc = 0; kc < K; kc += 64) {
        __syncthreads();
        { int r = tid >> 4, c = (tid & 15)*4;
          *(float4*)&xs[r][c] = *(const float4*)&A[(size_t)(m0+r)*lda + kc + c]; }
        __syncthreads();
        #pragma unroll 8
        for (int kk = 0; kk < 64; ++kk) {
            const float2 w = *(const float2*)&Bm[(size_t)(kc+kk)*ldb + n];
            const float xa = xs[bl][kk], xb = xs[bl+8][kk];
            a0x += xa*w.x; a0y += xa*w.y;
            a1x += xb*w.x; a1y += xb*w.y;
        }
    }
    float bx=0.f, by=0.f;
    if (bias){ bx = bias[n]; by = bias[n+1]; }
    float* c0 = &C[(size_t)(m0+bl)*ldc + n];
    float* c1 = &C[(size_t)(m0+bl+8)*ldc + n];
    c0[0]=a0x+bx; c0[1]=a0y+by; c1[0]=a1x+bx; c1[1]=a1y+by;
}

// ---------------------------------------------------------------------------
// bps = bp + bqm @ Wp_s   (Wp_s = first 128 rows of Wp_l). 1 block x 512.
__global__ __launch_bounds__(512)
void bps_k(const float* __restrict__ bqm, const float* __restrict__ Wps,
           const float* __restrict__ bp, float* __restrict__ bps)
{
    const int n = threadIdx.x;
    float a = 0.f;
    #pragma unroll 8
    for (int k = 0; k < 128; ++k) a += bqm[k]*Wps[(size_t)k*512 + n];
    bps[n] = a + bp[n];
}

// ---------------------------------------------------------------------------
// qp[cz][128][512] partial of (det @ Wq[0:1024] + obs @ Wq[1024:1536]).
// cz 0..3 -> det K-chunk cz*256 ; cz 4..5 -> obs K-chunk (cz-4)*256.
// grid (8, 16, 6), block 256.  (byte-identical to R3-verified version)
__global__ __launch_bounds__(256)
void qh_part_k(const float* __restrict__ det, long ld_det,   // pre-offset, step t-1
               const float* __restrict__ obs, long ld_obs,   // pre-offset, step t-1
               const float* __restrict__ Wq,                  // 1536 x 512
               float* __restrict__ qp)                        // 6 x 128 x 512
{
    __shared__ float xs[8][256];
    const int tid = threadIdx.x;
    const int nl = tid & 31, mg = tid >> 5;
    const int n  = blockIdx.x*64 + nl*2;
    const int m0 = blockIdx.y*8;
    const int cz = blockIdx.z;
    const float* As; long lda; int kr0;
    if (cz < 4) { As = det + cz*256;     lda = ld_det; kr0 = cz*256; }
    else        { As = obs + (cz-4)*256; lda = ld_obs; kr0 = 1024 + (cz-4)*256; }
    {   // stage A-tile 8 rows x 256 cols
        const int r = tid >> 5, c = (tid & 31)*8;
        const float* src = &As[(size_t)(m0+r)*lda + c];
        *(float4*)&xs[r][c]   = *(const float4*)&src[0];
        *(float4*)&xs[r][c+4] = *(const float4*)&src[4];
    }
    __syncthreads();
    const float* w = &Wq[(size_t)kr0*512 + n];
    float ax=0.f, ay=0.f;
    #pragma unroll 8
    for (int kk = 0; kk < 256; ++kk) {
        const float2 wv = *(const float2*)&w[(size_t)kk*512];
        const float x = xs[mg][kk];
        ax += x*wv.x; ay += x*wv.y;
    }
    *(float2*)&qp[(size_t)cz*65536 + (size_t)(m0+mg)*512 + n] = make_float2(ax, ay);
}

// ---------------------------------------------------------------------------
// hp[kz][128][512] partial of qh @ Wqs, where qh = relu(sum_c qp[c] + bq)
// is materialized during the A-stage. grid (8, 16, 4), block 256.
// (byte-identical to R3-verified version)
__global__ __launch_bounds__(256)
void h_part_k(const float* __restrict__ qp, const float* __restrict__ bq,
              const float* __restrict__ Wqs, float* __restrict__ hp)
{
    __shared__ float xs[8][128];
    const int tid = threadIdx.x;
    const int nl = tid & 31, mg = tid >> 5;
    const int n  = blockIdx.x*64 + nl*2;
    const int m0 = blockIdx.y*8;
    const int kz = blockIdx.z;
    {   // stage: qh[m0..m0+7][kz*128 .. +127] = relu(sum qp + bq)
        const int r = tid >> 5, c = (tid & 31)*4;
        const int kg = kz*128 + c;
        float4 s = *(const float4*)&bq[kg];
        #pragma unroll
        for (int cc = 0; cc < 6; ++cc) {
            const float4 p = *(const float4*)&qp[(size_t)cc*65536 + (size_t)(m0+r)*512 + kg];
            s.x += p.x; s.y += p.y; s.z += p.z; s.w += p.w;
        }
        s.x = fmaxf(s.x,0.f); s.y = fmaxf(s.y,0.f);
        s.z = fmaxf(s.z,0.f); s.w = fmaxf(s.w,0.f);
        *(float4*)&xs[r][c] = s;
    }
    __syncthreads();
    const float* w = &Wqs[(size_t)(kz*128)*512 + n];
    float ax=0.f, ay=0.f;
    #pragma unroll 8
    for (int kk = 0; kk < 128; ++kk) {
        const float2 wv = *(const float2*)&w[(size_t)kk*512];
        const float x = xs[mg][kk];
        ax += x*wv.x; ay += x*wv.y;
    }
    *(float2*)&hp[(size_t)kz*65536 + (size_t)(m0+mg)*512 + n] = make_float2(ax, ay);
}

// ---------------------------------------------------------------------------
// GRU partial GEMMs — 64 rows per block (halves weight re-reads vs R3's 32).
//   zc<4 : giP[zc] = (h-tile) @ Wih K-chunk zc*128, h built in A-stage
//   zc>=4: ghP[zc-4] = det @ Whh K-chunk (zc-4)*128
// grid (24, 2, 12), block 256. Thread: 8 rows x 4 cols (32 accs); kk unrolled
// x4: LDS acts as ds_read_b128 broadcast, weights as global dwordx4.
// 128 FMA per {8 DS + 4 VMEM} vs R3's 64 per {4+4}. Weight amp 16x -> 8x.
__global__ __launch_bounds__(256)
void gru_part_k(const float* __restrict__ hp,       // 4x128x512, or null (t==0)
                const float* __restrict__ hc, long ld_hc,  // pre-offset; or null
                const float* __restrict__ hbias,    // bps (t>0) or bp (t==0)
                const float* __restrict__ det, long ld_det,
                const float* __restrict__ Wih, const float* __restrict__ Whh,
                float* __restrict__ giP, float* __restrict__ ghP)
{
    __shared__ float xs[64*132];                     // 33.8 KB
    const int tid = threadIdx.x;
    const int nl = tid & 31, mg = tid >> 5;
    const int n  = blockIdx.x*128 + nl*4;            // 24 x-blocks cover 3072
    const int m0 = blockIdx.y*64;                    // 2 y-blocks cover 128 rows
    const int zc = blockIdx.z;
    const bool is_gi = (zc < 4);
    {   // stage A-tile 64 rows x 128 cols: r = tid>>2, 4 thr x 32 cols (R1-verified)
        const int r = tid >> 2, c0 = (tid & 3)*32;
        if (is_gi) {
            const int kb = zc*128;
            #pragma unroll
            for (int i = 0; i < 8; ++i) {
                const int c = c0 + i*4, kg = kb + c;
                float4 s = *(const float4*)&hbias[kg];
                if (hc) {
                    const float4 p = *(const float4*)&hc[(size_t)(m0+r)*ld_hc + kg];
                    s.x+=p.x; s.y+=p.y; s.z+=p.z; s.w+=p.w;
                }
                if (hp) {
                    #pragma unroll
                    for (int cc = 0; cc < 4; ++cc) {
                        const float4 p = *(const float4*)&hp[(size_t)cc*65536 + (size_t)(m0+r)*512 + kg];
                        s.x+=p.x; s.y+=p.y; s.z+=p.z; s.w+=p.w;
                    }
                }
                s.x=fmaxf(s.x,0.f); s.y=fmaxf(s.y,0.f);
                s.z=fmaxf(s.z,0.f); s.w=fmaxf(s.w,0.f);
                *(float4*)&xs[r*132 + c] = s;
            }
        } else {
            const int kb = (zc-4)*128;
            #pragma unroll
            for (int i = 0; i < 8; ++i) {
                const int c = c0 + i*4;
                *(float4*)&xs[r*132 + c] =
                    *(const float4*)&det[(size_t)(m0+r)*ld_det + kb + c];
            }
        }
    }
    __syncthreads();
    const float* W; float* outp;
    if (is_gi) { W = Wih + (size_t)(zc*128)*G3 + n;     outp = giP + (size_t)zc*393216; }
    else       { W = Whh + (size_t)((zc-4)*128)*G3 + n; outp = ghP + (size_t)(zc-4)*393216; }
    float4 acc[8];
    #pragma unroll
    for (int j = 0; j < 8; ++j) acc[j] = make_float4(0.f,0.f,0.f,0.f);
    const int rb = mg*8;                             // 8 rows per thread
    for (int kc4 = 0; kc4 < 128; kc4 += 4) {
        float4 wv[4];
        #pragma unroll
        for (int kk = 0; kk < 4; ++kk)
            wv[kk] = *(const float4*)&W[(size_t)(kc4+kk)*G3];
        #pragma unroll
        for (int j = 0; j < 8; ++j) {
            const float4 xv = *(const float4*)&xs[(rb+j)*132 + kc4];  // b128 broadcast
            acc[j].x += xv.x*wv[0].x; acc[j].y += xv.x*wv[0].y;
            acc[j].z += xv.x*wv[0].z; acc[j].w += xv.x*wv[0].w;
            acc[j].x += xv.y*wv[1].x; acc[j].y += xv.y*wv[1].y;
            acc[j].z += xv.y*wv[1].z; acc[j].w += xv.y*wv[1].w;
            acc[j].x += xv.z*wv[2].x; acc[j].y += xv.z*wv[2].y;
            acc[j].z += xv.z*wv[2].z; acc[j].w += xv.z*wv[2].w;
            acc[j].x += xv.w*wv[3].x; acc[j].y += xv.w*wv[3].y;
            acc[j].z += xv.w*wv[3].z; acc[j].w += xv.w*wv[3].w;
        }
    }
    #pragma unroll
    for (int j = 0; j < 8; ++j)
        *(float4*)&outp[(size_t)(m0+rb+j)*G3 + n] = acc[j];
}

// ---------------------------------------------------------------------------
// GRU pointwise from partials (4 gi + 8 gh chunks). grid (4, 128), block 256.
// (byte-identical to R3-verified version)
__global__ __launch_bounds__(256)
void gru_epi_k(const float* __restrict__ giP, const float* __restrict__ ghP,
               const float* __restrict__ bih, const float* __restrict__ bhh,
               const float* __restrict__ det_in, long ld_det,
               float* __restrict__ det_out, long ld_out)
{
    const int d = blockIdx.x*256 + threadIdx.x;
    const int b = blockIdx.y;
    float gir=0.f, giz=0.f, gin=0.f;
    #pragma unroll
    for (int c = 0; c < 4; ++c) {
        const float* p = &giP[(size_t)c*393216 + (size_t)b*G3 + d];
        gir += p[0]; giz += p[1024]; gin += p[2048];
    }
    float ghr=0.f, ghz=0.f, ghn=0.f;
    #pragma unroll
    for (int c = 0; c < 8; ++c) {
        const float* p = &ghP[(size_t)c*393216 + (size_t)b*G3 + d];
        ghr += p[0]; ghz += p[1024]; ghn += p[2048];
    }
    const float r  = sigmoidf_(gir + ghr + bih[d] + bhh[d]);
    const float z  = sigmoidf_(giz + ghz + bih[1024+d] + bhh[1024+d]);
    const float nn = tanhf(gin + bih[2048+d] + r*(ghn + bhh[2048+d]));
    const float dold = det_in[(size_t)b*ld_det + d];
    det_out[(size_t)b*ld_out + d] = (1.f - z)*nn + z*dold;
}

// ---------------------------------------------------------------------------
extern "C" void kernel_launch(void* const* d_in, const int* in_sizes, int n_in,
                              void* d_out, int out_size, void* d_ws, size_t ws_size,
                              hipStream_t stream)
{
    const float* obs0 = (const float*)d_in[0];
    const float* obs1 = (const float*)d_in[1];
    const float* obs2 = (const float*)d_in[2];
    const float* Wp   = (const float*)d_in[3];
    const float* bp   = (const float*)d_in[4];
    const float* Wih  = (const float*)d_in[5];
    const float* Whh  = (const float*)d_in[6];
    const float* bih  = (const float*)d_in[7];
    const float* bhh  = (const float*)d_in[8];
    const float* Wq   = (const float*)d_in[9];
    const float* bq   = (const float*)d_in[10];
    const float* Wqm  = (const float*)d_in[11];
    const float* bqm  = (const float*)d_in[12];

    float* ws = (float*)d_ws;
    float* det0 = ws;  ws += (size_t)128*1024;      // zero initial state
    float* WqsA = ws;  ws += (size_t)3*512*512;     // folded Wqm@Wp_s per level
    float* bpsA = ws;  ws += (size_t)3*512;         // folded bias per level
    float* dets2= ws;  ws += (size_t)128*16*1024;
    float* dets1= ws;  ws += (size_t)128*64*1024;
    float* HCu  = ws;  ws += (size_t)128*64*512;    // ctx@Wpc per level (reused)
    float* qp   = ws;  ws += (size_t)6*128*512;     // qh partials (6 K-chunks)
    float* hp   = ws;  ws += (size_t)4*128*512;     // h partials (4 K-chunks)
    float* giP  = ws;  ws += (size_t)4*128*3072;    // gi partials (4 K-chunks)
    float* ghP  = ws;  ws += (size_t)8*128*3072;    // gh partials (8 K-chunks)

    zero_k<<<dim3(128), dim3(256), 0, stream>>>(det0, 128*1024);

    // Per-level precompute: Wqs = Wqm @ Wp_s ; bps = bp + bqm @ Wp_s
    for (int l = 0; l < 3; ++l) {
        const float* Wp_l = Wp + (size_t)l*1152*512;
        gemm_k<<<dim3(8,32), dim3(256), 0, stream>>>(
            Wqm + (size_t)l*512*128, 128, Wp_l, 512, nullptr,
            WqsA + (size_t)l*512*512, 512, 128);
        bps_k<<<dim3(1), dim3(512), 0, stream>>>(
            bqm + (size_t)l*128, Wp_l, bp + (size_t)l*512, bpsA + (size_t)l*512);
    }

    const float* obsv[3] = {obs0, obs1, obs2};
    const int Tv[3] = {256, 64, 16};

    for (int level = 2; level >= 0; --level) {
        const int T = Tv[level];
        const float* o = obsv[level];
        float* dseq = (level == 0) ? (float*)d_out : (level == 1 ? dets1 : dets2);
        const float* ctxd = (level == 2) ? nullptr : (level == 1 ? dets2 : dets1);
        const int Tc = (level == 1) ? 16 : 64;

        const float* Wp_l  = Wp  + (size_t)level*1152*512;
        const float* Wpc_l = Wp_l + (size_t)128*512;     // ctx rows of Wp
        const float* bp_l  = bp  + (size_t)level*512;
        const float* Wih_l = Wih + (size_t)level*512*3072;
        const float* Whh_l = Whh + (size_t)level*1024*3072;
        const float* bih_l = bih + (size_t)level*3072;
        const float* bhh_l = bhh + (size_t)level*3072;
        const float* Wq_l  = Wq  + (size_t)level*1536*512;
        const float* bq_l  = bq  + (size_t)level*512;
        const float* Wqs_l = WqsA + (size_t)level*512*512;
        const float* bps_l = bpsA + (size_t)level*512;

        // Hoisted: HCu[(b*Tc+tc)][512] = ctx @ Wpc (previous level's output final)
        if (level < 2) {
            gemm_k<<<dim3(8, (128*Tc)/16), dim3(256), 0, stream>>>(
                ctxd, 1024, Wpc_l, 512, nullptr, HCu, 512, 1024);
        }

        for (int t = 0; t < T; ++t) {
            if (t > 0) {
                qh_part_k<<<dim3(8,16,6), dim3(256), 0, stream>>>(
                    dseq + (size_t)(t-1)*1024, (long)T*1024,
                    o + (size_t)(t-1)*512,  (long)T*512, Wq_l, qp);
                h_part_k<<<dim3(8,16,4), dim3(256), 0, stream>>>(qp, bq_l, Wqs_l, hp);
            }
            const float* hc_t  = (level < 2) ? HCu + (size_t)(t % Tc)*512 : nullptr;
            const float* dprev = t ? dseq + (size_t)(t-1)*1024 : det0;
            const long   ldprev = t ? (long)T*1024 : 1024L;
            gru_part_k<<<dim3(24,2,12), dim3(256), 0, stream>>>(
                t ? hp : nullptr, hc_t, (long)Tc*512,
                t ? bps_l : bp_l, dprev, ldprev,
                Wih_l, Whh_l, giP, ghP);
            gru_epi_k<<<dim3(4,128), dim3(256), 0, stream>>>(
                giP, ghP, bih_l, bhh_l, dprev, ldprev,
                dseq + (size_t)t*1024, (long)T*1024);
        }
    }
}